// Round 7
// baseline (164.496 us; speedup 1.0000x reference)
//
#include <hip/hip_runtime.h>
#include <hip/hip_bf16.h>

// MaskedAttentionHead: x[4,4096,1024] fp32 -> out fp32 [4,4096,64]
// Round 6: attn processes 128 keys/iter (pair of 64-tiles in the two LDS buffers):
// halves per-key softmax/barrier/loop overhead, 32 MFMA per barrier window.
// Exact triangular grid (640 blocks, LPT order). proj/prep_w/combine unchanged.

typedef _Float16 f16;
typedef f16 half4 __attribute__((ext_vector_type(4)));
typedef f16 half8 __attribute__((ext_vector_type(8)));
typedef float f32x4 __attribute__((ext_vector_type(4)));

#define T_SEQ 4096
// 0.125 (1/sqrt(64)) * log2(e): softmax computed in exp2 domain
#define QSCL 0.1803368801111204f

__device__ __forceinline__ f32x4 mfma16(half8 a, half8 b, f32x4 c) {
    return __builtin_amdgcn_mfma_f32_16x16x32_f16(a, b, c, 0, 0, 0);
}

// ---- Kernel 1: pack W into fragment order Wfrag[nt][ks][lane][8] f16 ----
__global__ __launch_bounds__(256) void prep_w(const float* __restrict__ Wq,
                                              const float* __restrict__ Wk,
                                              const float* __restrict__ Wv,
                                              f16* __restrict__ Wfrag) {
    int nt = blockIdx.x;               // 0..11
    int mat = nt >> 2;
    const float* W = (mat == 0) ? Wq : (mat == 1 ? Wk : Wv);
    float s = (mat == 0) ? QSCL : 1.0f;
    int tid = threadIdx.x;
    int lane = tid & 63, g = lane >> 4, c16 = lane & 15;
    int ksb = (tid >> 6) * 8;
    int h = ((nt & 3) << 4) + c16;
#pragma unroll
    for (int q = 0; q < 8; ++q) {
        int ks = ksb + q;
        half8 o;
#pragma unroll
        for (int j = 0; j < 8; ++j) {
            int k = ks * 32 + g * 8 + j;
            o[j] = (f16)(W[(size_t)k * 64 + h] * s);
        }
        *reinterpret_cast<half8*>(&Wfrag[((size_t)(nt * 32 + ks) * 64 + lane) * 8]) = o;
    }
}

// ---- Kernel 2: QKV projection with one-shot LDS x-staging (unchanged) ----
__global__ __launch_bounds__(256, 4) void proj(const float* __restrict__ x,
                                               const f16* __restrict__ Wfrag,
                                               const float* __restrict__ bk,
                                               const float* __restrict__ bq,
                                               const float* __restrict__ bv,
                                               f16* __restrict__ Qb, f16* __restrict__ Kb,
                                               f16* __restrict__ Vbt) {
    __shared__ f16 xs[16][1032];
    int m0 = blockIdx.x << 4;
    int tid = threadIdx.x;
    int w = tid >> 6, lane = tid & 63, g = lane >> 4, c16 = lane & 15;
    {
        int row = tid >> 4;
        int c0 = (tid & 15) << 2;
        const float* xr = &x[(size_t)(m0 + row) * 1024 + c0];
#pragma unroll
        for (int chunk = 0; chunk < 8; ++chunk) {
            float4 A = *reinterpret_cast<const float4*>(xr + chunk * 128);
            float4 B = *reinterpret_cast<const float4*>(xr + chunk * 128 + 64);
            half4 ha, hb;
            ha[0] = (f16)A.x; ha[1] = (f16)A.y; ha[2] = (f16)A.z; ha[3] = (f16)A.w;
            hb[0] = (f16)B.x; hb[1] = (f16)B.y; hb[2] = (f16)B.z; hb[3] = (f16)B.w;
            *reinterpret_cast<half4*>(&xs[row][c0 + chunk * 128]) = ha;
            *reinterpret_cast<half4*>(&xs[row][c0 + chunk * 128 + 64]) = hb;
        }
    }
    __syncthreads();
    f32x4 zero = {0.f, 0.f, 0.f, 0.f};
    f32x4 acc[3];
#pragma unroll
    for (int i = 0; i < 3; ++i) acc[i] = zero;
    const f16* wbase = &Wfrag[(size_t)(w * 3) * 32 * 64 * 8 + (size_t)lane * 8];
#pragma unroll 8
    for (int ks = 0; ks < 32; ++ks) {
        half8 a = *reinterpret_cast<const half8*>(&xs[c16][ks * 32 + g * 8]);
#pragma unroll
        for (int i = 0; i < 3; ++i) {
            half8 bf = *reinterpret_cast<const half8*>(
                wbase + ((size_t)i * 32 + ks) * 64 * 8);
            acc[i] = mfma16(a, bf, acc[i]);
        }
    }
    int b = m0 >> 12;
#pragma unroll
    for (int i = 0; i < 3; ++i) {
        int nt = w * 3 + i;
        int mat = nt >> 2;
        int h = ((nt & 3) << 4) + c16;
        float bias = (mat == 0) ? bq[h] * QSCL : (mat == 1 ? bk[h] : bv[h]);
#pragma unroll
        for (int j = 0; j < 4; ++j) {
            int row = m0 + g * 4 + j;
            f16 val = (f16)(acc[i][j] + bias);
            if (mat == 0) Qb[(size_t)row * 64 + h] = val;
            else if (mat == 1) Kb[(size_t)row * 64 + h] = val;
            else Vbt[((size_t)(b * 64 + h)) * 4096 + (row & 4095)] = val;
        }
    }
}

// ---- Kernel 3: flash attention, 128 keys/iter, S^T in-lane softmax ----
__global__ __launch_bounds__(256) void attn(const f16* __restrict__ Qb,
                                            const f16* __restrict__ Kb,
                                            const f16* __restrict__ Vbt,
                                            f16* __restrict__ Opart,
                                            float* __restrict__ Ml) {
    // exact triangular grid: 160 (qt,ck) pairs, LPT (16-tile chunks first)
    int idx = 159 - (int)blockIdx.x;
    int qt, ck;
    if (idx < 16) { qt = idx; ck = 0; }
    else if (idx < 48) { int j = idx - 16; qt = 16 + (j >> 1); ck = j & 1; }
    else if (idx < 96) { int j = idx - 48; int q3 = j / 3; qt = 32 + q3; ck = j - 3 * q3; }
    else { int j = idx - 96; qt = 48 + (j >> 2); ck = j & 3; }
    int b = blockIdx.y;
    int nT = min(16, qt + 1 - (ck << 4));
    int npairs = (nT + 1) >> 1;
    int kend = ((ck << 4) + nT) << 6;      // first invalid key
    int q0 = qt << 6;
    const f16* Q = Qb + (size_t)b * T_SEQ * 64;
    const f16* K = Kb + (size_t)b * T_SEQ * 64;
    const f16* Vg = Vbt + (size_t)b * 64 * T_SEQ;
    int tid = threadIdx.x;
    int w = tid >> 6, lane = tid & 63, g = lane >> 4, c16 = lane & 15;
    __shared__ f16 Kt[2][64][72];   // halves of the 128-key tile: [key][h]
    __shared__ f16 Vt[2][64][72];   // [h][key-local]
    __shared__ f16 Pl[4][16][136];  // [wave][qrow][key 0..127]

    int qr = q0 + 16 * w + c16;     // this lane's q-row
    half8 qf0 = *reinterpret_cast<const half8*>(&Q[(size_t)qr * 64 + g * 8]);
    half8 qf1 = *reinterpret_cast<const half8*>(&Q[(size_t)qr * 64 + 32 + g * 8]);

    f32x4 zero = {0.f, 0.f, 0.f, 0.f};
    f32x4 oacc[4];                  // O^T: oacc[ht][jj] = O[qr][ht*16+g*4+jj]
#pragma unroll
    for (int i = 0; i < 4; ++i) oacc[i] = zero;
    float m_run = -__builtin_inff(), l_run = 0.f;

    int sr = tid >> 2, sc = (tid & 3) << 4;
    // ---- stage pair 0 ----
    int kb0 = ck << 10;
    half8 k00, k01, k10, k11, v00, v01, v10, v11;
    {
        const f16* Kp = &K[(size_t)(kb0 + sr) * 64 + sc];
        k00 = *reinterpret_cast<const half8*>(Kp);
        k01 = *reinterpret_cast<const half8*>(Kp + 8);
        k10 = *reinterpret_cast<const half8*>(Kp + 64 * 64);
        k11 = *reinterpret_cast<const half8*>(Kp + 64 * 64 + 8);
        const f16* Vp = &Vg[(size_t)sr * T_SEQ + kb0 + sc];
        v00 = *reinterpret_cast<const half8*>(Vp);
        v01 = *reinterpret_cast<const half8*>(Vp + 8);
        v10 = *reinterpret_cast<const half8*>(Vp + 64);
        v11 = *reinterpret_cast<const half8*>(Vp + 64 + 8);
    }
    *reinterpret_cast<half8*>(&Kt[0][sr][sc]) = k00;
    *reinterpret_cast<half8*>(&Kt[0][sr][sc + 8]) = k01;
    *reinterpret_cast<half8*>(&Kt[1][sr][sc]) = k10;
    *reinterpret_cast<half8*>(&Kt[1][sr][sc + 8]) = k11;
    *reinterpret_cast<half8*>(&Vt[0][sr][sc]) = v00;
    *reinterpret_cast<half8*>(&Vt[0][sr][sc + 8]) = v01;
    *reinterpret_cast<half8*>(&Vt[1][sr][sc]) = v10;
    *reinterpret_cast<half8*>(&Vt[1][sr][sc + 8]) = v11;
    __syncthreads();

    for (int p = 0; p < npairs; ++p) {
        bool pre = (p + 1 < npairs);
        if (pre) {      // issue next pair's global loads early
            int kb2 = (ck << 10) + ((p + 1) << 7);
            const f16* Kp = &K[(size_t)(kb2 + sr) * 64 + sc];
            k00 = *reinterpret_cast<const half8*>(Kp);
            k01 = *reinterpret_cast<const half8*>(Kp + 8);
            k10 = *reinterpret_cast<const half8*>(Kp + 64 * 64);
            k11 = *reinterpret_cast<const half8*>(Kp + 64 * 64 + 8);
            const f16* Vp = &Vg[(size_t)sr * T_SEQ + kb2 + sc];
            v00 = *reinterpret_cast<const half8*>(Vp);
            v01 = *reinterpret_cast<const half8*>(Vp + 8);
            v10 = *reinterpret_cast<const half8*>(Vp + 64);
            v11 = *reinterpret_cast<const half8*>(Vp + 64 + 8);
        }
        // ---- S^T = K · Q^T over 128 keys: lane holds S[qr][key=nt*16+g*4+jj] ----
        f32x4 st[8];
#pragma unroll
        for (int nt = 0; nt < 8; ++nt) st[nt] = zero;
#pragma unroll
        for (int nt = 0; nt < 8; ++nt) {
            const f16* kr = &Kt[nt >> 2][((nt & 3) << 4) + c16][0];
            half8 kf0 = *reinterpret_cast<const half8*>(kr + g * 8);
            half8 kf1 = *reinterpret_cast<const half8*>(kr + 32 + g * 8);
            st[nt] = mfma16(kf0, qf0, st[nt]);
            st[nt] = mfma16(kf1, qf1, st[nt]);
        }
        // ---- causal / range mask (only last pair of chunk can straddle) ----
        if (p == npairs - 1) {
            int kbp = (ck << 10) + (p << 7);
            int keylim = min(qr, kend - 1);
#pragma unroll
            for (int nt = 0; nt < 8; ++nt)
#pragma unroll
                for (int jj = 0; jj < 4; ++jj)
                    if (kbp + nt * 16 + g * 4 + jj > keylim) st[nt][jj] = -1e30f;
        }
        // ---- softmax over 32 in-lane values + cross-g reduce ----
        float mx;
        {
            f32x4 e01 = __builtin_elementwise_max(st[0], st[1]);
            f32x4 e23 = __builtin_elementwise_max(st[2], st[3]);
            f32x4 e45 = __builtin_elementwise_max(st[4], st[5]);
            f32x4 e67 = __builtin_elementwise_max(st[6], st[7]);
            f32x4 e = __builtin_elementwise_max(__builtin_elementwise_max(e01, e23),
                                                __builtin_elementwise_max(e45, e67));
            mx = fmaxf(fmaxf(e[0], e[1]), fmaxf(e[2], e[3]));
        }
        mx = fmaxf(mx, __shfl_xor(mx, 16, 64));
        mx = fmaxf(mx, __shfl_xor(mx, 32, 64));
        float nm = fmaxf(m_run, mx);
        float al = exp2f(m_run - nm);
        m_run = nm;
        float rs = 0.f;
#pragma unroll
        for (int nt = 0; nt < 8; ++nt) {
            float s0 = exp2f(st[nt][0] - m_run);
            float s1 = exp2f(st[nt][1] - m_run);
            float s2 = exp2f(st[nt][2] - m_run);
            float s3 = exp2f(st[nt][3] - m_run);
            st[nt][0] = s0; st[nt][1] = s1; st[nt][2] = s2; st[nt][3] = s3;
            rs += (s0 + s1) + (s2 + s3);
        }
        rs += __shfl_xor(rs, 16, 64);
        rs += __shfl_xor(rs, 32, 64);
        l_run = l_run * al + rs;
#pragma unroll
        for (int ht = 0; ht < 4; ++ht)
#pragma unroll
            for (int jj = 0; jj < 4; ++jj) oacc[ht][jj] *= al;
        // ---- P^T pack: 8x half4 (keys 4-contiguous per lane) ----
#pragma unroll
        for (int nt = 0; nt < 8; ++nt) {
            half4 p4;
            p4[0] = (f16)st[nt][0]; p4[1] = (f16)st[nt][1];
            p4[2] = (f16)st[nt][2]; p4[3] = (f16)st[nt][3];
            *reinterpret_cast<half4*>(&Pl[w][c16][nt * 16 + g * 4]) = p4;
        }
        // ---- PV: O^T += V^T · P^T over 128 keys ----
#pragma unroll
        for (int s = 0; s < 4; ++s) {
            half8 pa = *reinterpret_cast<const half8*>(&Pl[w][c16][s * 32 + g * 8]);
#pragma unroll
            for (int ht = 0; ht < 4; ++ht) {
                half8 vb = *reinterpret_cast<const half8*>(
                    &Vt[s >> 1][ht * 16 + c16][(s & 1) * 32 + g * 8]);
                oacc[ht] = mfma16(vb, pa, oacc[ht]);
            }
        }
        __syncthreads();
        if (pre) {      // write prefetched pair into LDS
            *reinterpret_cast<half8*>(&Kt[0][sr][sc]) = k00;
            *reinterpret_cast<half8*>(&Kt[0][sr][sc + 8]) = k01;
            *reinterpret_cast<half8*>(&Kt[1][sr][sc]) = k10;
            *reinterpret_cast<half8*>(&Kt[1][sr][sc + 8]) = k11;
            *reinterpret_cast<half8*>(&Vt[0][sr][sc]) = v00;
            *reinterpret_cast<half8*>(&Vt[0][sr][sc + 8]) = v01;
            *reinterpret_cast<half8*>(&Vt[1][sr][sc]) = v10;
            *reinterpret_cast<half8*>(&Vt[1][sr][sc + 8]) = v11;
            __syncthreads();
        }
    }
    // ---- epilogue: partial O (f16) + m/l ----
    int slot = (((b << 6) + qt) << 2) + ck;
    f16* Op = Opart + (size_t)slot * 4096;
    float* mlp = Ml + (size_t)slot * 128;
    int r = 16 * w + c16;
#pragma unroll
    for (int ht = 0; ht < 4; ++ht) {
        half4 o4;
        o4[0] = (f16)oacc[ht][0]; o4[1] = (f16)oacc[ht][1];
        o4[2] = (f16)oacc[ht][2]; o4[3] = (f16)oacc[ht][3];
        *reinterpret_cast<half4*>(&Op[r * 64 + ht * 16 + g * 4]) = o4;
    }
    if (g == 0) { mlp[r] = m_run; mlp[64 + r] = l_run; }
}

// ---- Kernel 4: combine split-KV partials (exp2 domain) ----
__global__ __launch_bounds__(256) void combine(const f16* __restrict__ Opart,
                                               const float* __restrict__ Ml,
                                               float* __restrict__ out) {
    int qt = blockIdx.x, b = blockIdx.y;
    int nck = (qt >> 4) + 1;
    int tid = threadIdx.x;
    int row = tid >> 2, c0 = (tid & 3) << 4;
    int bslot = ((b << 6) + qt) << 2;
    float mv[4], lv[4];
    float M = -1e30f;
#pragma unroll
    for (int i = 0; i < 4; ++i)
        if (i < nck) {
            mv[i] = Ml[(size_t)(bslot + i) * 128 + row];
            lv[i] = Ml[(size_t)(bslot + i) * 128 + 64 + row];
            M = fmaxf(M, mv[i]);
        }
    float L = 0.f, sc[4];
#pragma unroll
    for (int i = 0; i < 4; ++i)
        if (i < nck) { sc[i] = exp2f(mv[i] - M); L += lv[i] * sc[i]; }
    float inv = 1.0f / L;
    float o[16];
#pragma unroll
    for (int j = 0; j < 16; ++j) o[j] = 0.f;
#pragma unroll
    for (int i = 0; i < 4; ++i)
        if (i < nck) {
            const f16* Op = Opart + (size_t)(bslot + i) * 4096 + row * 64 + c0;
            half8 h0 = *reinterpret_cast<const half8*>(Op);
            half8 h1 = *reinterpret_cast<const half8*>(Op + 8);
#pragma unroll
            for (int j = 0; j < 8; ++j) {
                o[j] += sc[i] * (float)h0[j];
                o[8 + j] += sc[i] * (float)h1[j];
            }
        }
    float* op = &out[((size_t)b * T_SEQ + (qt << 6) + row) * 64 + c0];
#pragma unroll
    for (int j = 0; j < 16; ++j) op[j] = o[j] * inv;
}

extern "C" void kernel_launch(void* const* d_in, const int* in_sizes, int n_in,
                              void* d_out, int out_size, void* d_ws, size_t ws_size,
                              hipStream_t stream) {
    (void)in_sizes; (void)n_in; (void)out_size; (void)ws_size;
    const float* x  = (const float*)d_in[0];
    const float* Wk = (const float*)d_in[1];
    const float* bk = (const float*)d_in[2];
    const float* Wq = (const float*)d_in[3];
    const float* bq = (const float*)d_in[4];
    const float* Wv = (const float*)d_in[5];
    const float* bv = (const float*)d_in[6];
    float* out = (float*)d_out;
    char* ws = (char*)d_ws;
    f16* Wfrag = (f16*)(ws);                        // 393216 B
    f16* Qb    = (f16*)(ws + 393216);               // 2 MiB
    f16* Kb    = (f16*)(ws + 393216 + 2097152);     // 2 MiB
    f16* Vbt   = (f16*)(ws + 393216 + 2 * 2097152); // 2 MiB (transposed)
    f16* Opart = (f16*)(ws + 393216 + 3 * 2097152);            // 8 MiB
    float* Ml  = (float*)(ws + 393216 + 3 * 2097152 + 8388608); // 512 KiB

    prep_w<<<12, 256, 0, stream>>>(Wq, Wk, Wv, Wfrag);
    proj<<<1024, 256, 0, stream>>>(x, Wfrag, bk, bq, bv, Qb, Kb, Vbt);
    attn<<<dim3(160, 4), 256, 0, stream>>>(Qb, Kb, Vbt, Opart, Ml);
    combine<<<dim3(64, 4), 256, 0, stream>>>(Opart, Ml, out);
}

// Round 8
// 157.562 us; speedup vs baseline: 1.0440x; 1.0440x over previous
//
#include <hip/hip_runtime.h>
#include <hip/hip_bf16.h>

// MaskedAttentionHead: x[4,4096,1024] fp32 -> out fp32 [4,4096,64]
// Round 7: revert attn inner loop to 64-key/iter (round-5 structure, 1 barrier/iter),
// split KV into 8 chunks of 8 tiles -> 1152 well-balanced blocks (work-limited grid).
// Combine merges up to 8 chunks. proj/prep_w unchanged.

typedef _Float16 f16;
typedef f16 half4 __attribute__((ext_vector_type(4)));
typedef f16 half8 __attribute__((ext_vector_type(8)));
typedef float f32x4 __attribute__((ext_vector_type(4)));

#define T_SEQ 4096
// 0.125 (1/sqrt(64)) * log2(e): softmax computed in exp2 domain
#define QSCL 0.1803368801111204f

__device__ __forceinline__ f32x4 mfma16(half8 a, half8 b, f32x4 c) {
    return __builtin_amdgcn_mfma_f32_16x16x32_f16(a, b, c, 0, 0, 0);
}

// ---- Kernel 1: pack W into fragment order Wfrag[nt][ks][lane][8] f16 ----
__global__ __launch_bounds__(256) void prep_w(const float* __restrict__ Wq,
                                              const float* __restrict__ Wk,
                                              const float* __restrict__ Wv,
                                              f16* __restrict__ Wfrag) {
    int nt = blockIdx.x;               // 0..11
    int mat = nt >> 2;
    const float* W = (mat == 0) ? Wq : (mat == 1 ? Wk : Wv);
    float s = (mat == 0) ? QSCL : 1.0f;
    int tid = threadIdx.x;
    int lane = tid & 63, g = lane >> 4, c16 = lane & 15;
    int ksb = (tid >> 6) * 8;
    int h = ((nt & 3) << 4) + c16;
#pragma unroll
    for (int q = 0; q < 8; ++q) {
        int ks = ksb + q;
        half8 o;
#pragma unroll
        for (int j = 0; j < 8; ++j) {
            int k = ks * 32 + g * 8 + j;
            o[j] = (f16)(W[(size_t)k * 64 + h] * s);
        }
        *reinterpret_cast<half8*>(&Wfrag[((size_t)(nt * 32 + ks) * 64 + lane) * 8]) = o;
    }
}

// ---- Kernel 2: QKV projection with one-shot LDS x-staging (unchanged) ----
__global__ __launch_bounds__(256, 4) void proj(const float* __restrict__ x,
                                               const f16* __restrict__ Wfrag,
                                               const float* __restrict__ bk,
                                               const float* __restrict__ bq,
                                               const float* __restrict__ bv,
                                               f16* __restrict__ Qb, f16* __restrict__ Kb,
                                               f16* __restrict__ Vbt) {
    __shared__ f16 xs[16][1032];
    int m0 = blockIdx.x << 4;
    int tid = threadIdx.x;
    int w = tid >> 6, lane = tid & 63, g = lane >> 4, c16 = lane & 15;
    {
        int row = tid >> 4;
        int c0 = (tid & 15) << 2;
        const float* xr = &x[(size_t)(m0 + row) * 1024 + c0];
#pragma unroll
        for (int chunk = 0; chunk < 8; ++chunk) {
            float4 A = *reinterpret_cast<const float4*>(xr + chunk * 128);
            float4 B = *reinterpret_cast<const float4*>(xr + chunk * 128 + 64);
            half4 ha, hb;
            ha[0] = (f16)A.x; ha[1] = (f16)A.y; ha[2] = (f16)A.z; ha[3] = (f16)A.w;
            hb[0] = (f16)B.x; hb[1] = (f16)B.y; hb[2] = (f16)B.z; hb[3] = (f16)B.w;
            *reinterpret_cast<half4*>(&xs[row][c0 + chunk * 128]) = ha;
            *reinterpret_cast<half4*>(&xs[row][c0 + chunk * 128 + 64]) = hb;
        }
    }
    __syncthreads();
    f32x4 zero = {0.f, 0.f, 0.f, 0.f};
    f32x4 acc[3];
#pragma unroll
    for (int i = 0; i < 3; ++i) acc[i] = zero;
    const f16* wbase = &Wfrag[(size_t)(w * 3) * 32 * 64 * 8 + (size_t)lane * 8];
#pragma unroll 8
    for (int ks = 0; ks < 32; ++ks) {
        half8 a = *reinterpret_cast<const half8*>(&xs[c16][ks * 32 + g * 8]);
#pragma unroll
        for (int i = 0; i < 3; ++i) {
            half8 bf = *reinterpret_cast<const half8*>(
                wbase + ((size_t)i * 32 + ks) * 64 * 8);
            acc[i] = mfma16(a, bf, acc[i]);
        }
    }
    int b = m0 >> 12;
#pragma unroll
    for (int i = 0; i < 3; ++i) {
        int nt = w * 3 + i;
        int mat = nt >> 2;
        int h = ((nt & 3) << 4) + c16;
        float bias = (mat == 0) ? bq[h] * QSCL : (mat == 1 ? bk[h] : bv[h]);
#pragma unroll
        for (int j = 0; j < 4; ++j) {
            int row = m0 + g * 4 + j;
            f16 val = (f16)(acc[i][j] + bias);
            if (mat == 0) Qb[(size_t)row * 64 + h] = val;
            else if (mat == 1) Kb[(size_t)row * 64 + h] = val;
            else Vbt[((size_t)(b * 64 + h)) * 4096 + (row & 4095)] = val;
        }
    }
}

// ---- Kernel 3: flash attention, 64 keys/iter, chunks of 8 KV tiles ----
// Exact triangular grid: 288 (qt,ck) pairs. Band bd (qt in [8bd,8bd+7]) has bd+1
// chunks per qt -> 8*(bd+1) entries; cumulative 4*bd*(bd+1).
__global__ __launch_bounds__(256) void attn(const f16* __restrict__ Qb,
                                            const f16* __restrict__ Kb,
                                            const f16* __restrict__ Vbt,
                                            f16* __restrict__ Opart,
                                            float* __restrict__ Ml) {
    int rem = 287 - (int)blockIdx.x;      // LPT: largest qt first
    int qt = 0, ck = 0;
    for (int bd = 0; bd < 8; ++bd) {
        int cnt = 8 * (bd + 1);
        if (rem < cnt) { qt = bd * 8 + rem / (bd + 1); ck = rem % (bd + 1); break; }
        rem -= cnt;
    }
    int b = blockIdx.y;
    int t0 = ck << 3;                      // first KV tile of this chunk
    int nIter = min(8, qt + 1 - t0);
    int q0 = qt << 6;
    const f16* Q = Qb + (size_t)b * T_SEQ * 64;
    const f16* K = Kb + (size_t)b * T_SEQ * 64;
    const f16* Vg = Vbt + (size_t)b * 64 * T_SEQ;
    int tid = threadIdx.x;
    int w = tid >> 6, lane = tid & 63, g = lane >> 4, c16 = lane & 15;
    __shared__ f16 Kt[2][64][72];   // [buf][key][h]
    __shared__ f16 Vt[2][64][72];   // [buf][h][key]
    __shared__ f16 Pl[4][16][72];   // [wave][qrow][key]

    int qr = q0 + 16 * w + c16;     // this lane's q-row
    half8 qf0 = *reinterpret_cast<const half8*>(&Q[(size_t)qr * 64 + g * 8]);
    half8 qf1 = *reinterpret_cast<const half8*>(&Q[(size_t)qr * 64 + 32 + g * 8]);

    f32x4 zero = {0.f, 0.f, 0.f, 0.f};
    f32x4 oacc[4];                  // O^T: oacc[ht][jj] = O[qr][ht*16+g*4+jj]
#pragma unroll
    for (int i = 0; i < 4; ++i) oacc[i] = zero;
    float m_run = -__builtin_inff(), l_run = 0.f;

    int sr = tid >> 2, sc = (tid & 3) << 4;
    int k0 = t0 << 6;
    half8 kr0 = *reinterpret_cast<const half8*>(&K[(size_t)(k0 + sr) * 64 + sc]);
    half8 kr1 = *reinterpret_cast<const half8*>(&K[(size_t)(k0 + sr) * 64 + sc + 8]);
    half8 vr0 = *reinterpret_cast<const half8*>(&Vg[(size_t)sr * T_SEQ + k0 + sc]);
    half8 vr1 = *reinterpret_cast<const half8*>(&Vg[(size_t)sr * T_SEQ + k0 + sc + 8]);
    *reinterpret_cast<half8*>(&Kt[0][sr][sc]) = kr0;
    *reinterpret_cast<half8*>(&Kt[0][sr][sc + 8]) = kr1;
    *reinterpret_cast<half8*>(&Vt[0][sr][sc]) = vr0;
    *reinterpret_cast<half8*>(&Vt[0][sr][sc + 8]) = vr1;
    __syncthreads();
    int cur = 0;

    for (int it = 0; it < nIter; ++it) {
        int gt = t0 + it;
        if (it + 1 < nIter) {
            int kn = (gt + 1) << 6;
            kr0 = *reinterpret_cast<const half8*>(&K[(size_t)(kn + sr) * 64 + sc]);
            kr1 = *reinterpret_cast<const half8*>(&K[(size_t)(kn + sr) * 64 + sc + 8]);
            vr0 = *reinterpret_cast<const half8*>(&Vg[(size_t)sr * T_SEQ + kn + sc]);
            vr1 = *reinterpret_cast<const half8*>(&Vg[(size_t)sr * T_SEQ + kn + sc + 8]);
        }
        // S^T = K · Q^T : lane holds S[qr][key = nt*16+g*4+jj]
        f32x4 st[4];
#pragma unroll
        for (int nt = 0; nt < 4; ++nt) st[nt] = zero;
#pragma unroll
        for (int nt = 0; nt < 4; ++nt) {
            half8 kf0 = *reinterpret_cast<const half8*>(&Kt[cur][nt * 16 + c16][g * 8]);
            half8 kf1 = *reinterpret_cast<const half8*>(&Kt[cur][nt * 16 + c16][32 + g * 8]);
            st[nt] = mfma16(kf0, qf0, st[nt]);
            st[nt] = mfma16(kf1, qf1, st[nt]);
        }
        if (gt == qt) {    // causal mask on diagonal tile
            int kb = gt << 6;
#pragma unroll
            for (int nt = 0; nt < 4; ++nt)
#pragma unroll
                for (int jj = 0; jj < 4; ++jj)
                    if (kb + nt * 16 + g * 4 + jj > qr) st[nt][jj] = -1e30f;
        }
        // in-lane max over 16 values, then cross-g reduce (2 shuffles)
        float mx;
        {
            f32x4 e01 = __builtin_elementwise_max(st[0], st[1]);
            f32x4 e23 = __builtin_elementwise_max(st[2], st[3]);
            f32x4 e = __builtin_elementwise_max(e01, e23);
            mx = fmaxf(fmaxf(e[0], e[1]), fmaxf(e[2], e[3]));
        }
        mx = fmaxf(mx, __shfl_xor(mx, 16, 64));
        mx = fmaxf(mx, __shfl_xor(mx, 32, 64));
        float nm = fmaxf(m_run, mx);
        float al = exp2f(m_run - nm);
        m_run = nm;
        float rs = 0.f;
#pragma unroll
        for (int nt = 0; nt < 4; ++nt) {
            float s0 = exp2f(st[nt][0] - m_run);
            float s1 = exp2f(st[nt][1] - m_run);
            float s2 = exp2f(st[nt][2] - m_run);
            float s3 = exp2f(st[nt][3] - m_run);
            st[nt][0] = s0; st[nt][1] = s1; st[nt][2] = s2; st[nt][3] = s3;
            rs += (s0 + s1) + (s2 + s3);
        }
        rs += __shfl_xor(rs, 16, 64);
        rs += __shfl_xor(rs, 32, 64);
        l_run = l_run * al + rs;
#pragma unroll
        for (int ht = 0; ht < 4; ++ht)
#pragma unroll
            for (int jj = 0; jj < 4; ++jj) oacc[ht][jj] *= al;
        // P^T pack: keys 4-contiguous per lane -> 4x b64 writes
#pragma unroll
        for (int nt = 0; nt < 4; ++nt) {
            half4 p4;
            p4[0] = (f16)st[nt][0]; p4[1] = (f16)st[nt][1];
            p4[2] = (f16)st[nt][2]; p4[3] = (f16)st[nt][3];
            *reinterpret_cast<half4*>(&Pl[w][c16][nt * 16 + g * 4]) = p4;
        }
        // PV: O^T += V^T · P^T
        half8 pa0 = *reinterpret_cast<const half8*>(&Pl[w][c16][g * 8]);
        half8 pa1 = *reinterpret_cast<const half8*>(&Pl[w][c16][32 + g * 8]);
#pragma unroll
        for (int ht = 0; ht < 4; ++ht) {
            half8 vb0 = *reinterpret_cast<const half8*>(&Vt[cur][ht * 16 + c16][g * 8]);
            half8 vb1 = *reinterpret_cast<const half8*>(&Vt[cur][ht * 16 + c16][32 + g * 8]);
            oacc[ht] = mfma16(vb0, pa0, oacc[ht]);
            oacc[ht] = mfma16(vb1, pa1, oacc[ht]);
        }
        if (it + 1 < nIter) {
            *reinterpret_cast<half8*>(&Kt[cur ^ 1][sr][sc]) = kr0;
            *reinterpret_cast<half8*>(&Kt[cur ^ 1][sr][sc + 8]) = kr1;
            *reinterpret_cast<half8*>(&Vt[cur ^ 1][sr][sc]) = vr0;
            *reinterpret_cast<half8*>(&Vt[cur ^ 1][sr][sc + 8]) = vr1;
        }
        __syncthreads();
        cur ^= 1;
    }
    // epilogue: partial O (f16, lane's qrow = qr, h = ht*16+g*4+jj) + m/l
    int slot = (((b << 6) + qt) << 3) + ck;
    f16* Op = Opart + (size_t)slot * 4096;
    float* mlp = Ml + (size_t)slot * 128;
    int r = 16 * w + c16;
#pragma unroll
    for (int ht = 0; ht < 4; ++ht) {
        half4 o4;
        o4[0] = (f16)oacc[ht][0]; o4[1] = (f16)oacc[ht][1];
        o4[2] = (f16)oacc[ht][2]; o4[3] = (f16)oacc[ht][3];
        *reinterpret_cast<half4*>(&Op[r * 64 + ht * 16 + g * 4]) = o4;
    }
    if (g == 0) { mlp[r] = m_run; mlp[64 + r] = l_run; }
}

// ---- Kernel 4: combine split-KV partials (exp2 domain, up to 8 chunks) ----
__global__ __launch_bounds__(256) void combine(const f16* __restrict__ Opart,
                                               const float* __restrict__ Ml,
                                               float* __restrict__ out) {
    int qt = blockIdx.x, b = blockIdx.y;
    int nck = (qt >> 3) + 1;
    int tid = threadIdx.x;
    int row = tid >> 2, c0 = (tid & 3) << 4;
    int bslot = ((b << 6) + qt) << 3;
    float mv[8], lv[8];
    float M = -1e30f;
#pragma unroll
    for (int i = 0; i < 8; ++i)
        if (i < nck) {
            mv[i] = Ml[(size_t)(bslot + i) * 128 + row];
            lv[i] = Ml[(size_t)(bslot + i) * 128 + 64 + row];
            M = fmaxf(M, mv[i]);
        }
    float L = 0.f, sc[8];
#pragma unroll
    for (int i = 0; i < 8; ++i)
        if (i < nck) { sc[i] = exp2f(mv[i] - M); L += lv[i] * sc[i]; }
    float inv = 1.0f / L;
    float o[16];
#pragma unroll
    for (int j = 0; j < 16; ++j) o[j] = 0.f;
#pragma unroll
    for (int i = 0; i < 8; ++i)
        if (i < nck) {
            const f16* Op = Opart + (size_t)(bslot + i) * 4096 + row * 64 + c0;
            half8 h0 = *reinterpret_cast<const half8*>(Op);
            half8 h1 = *reinterpret_cast<const half8*>(Op + 8);
#pragma unroll
            for (int j = 0; j < 8; ++j) {
                o[j] += sc[i] * (float)h0[j];
                o[8 + j] += sc[i] * (float)h1[j];
            }
        }
    float* op = &out[((size_t)b * T_SEQ + (qt << 6) + row) * 64 + c0];
#pragma unroll
    for (int j = 0; j < 16; ++j) op[j] = o[j] * inv;
}

extern "C" void kernel_launch(void* const* d_in, const int* in_sizes, int n_in,
                              void* d_out, int out_size, void* d_ws, size_t ws_size,
                              hipStream_t stream) {
    (void)in_sizes; (void)n_in; (void)out_size; (void)ws_size;
    const float* x  = (const float*)d_in[0];
    const float* Wk = (const float*)d_in[1];
    const float* bk = (const float*)d_in[2];
    const float* Wq = (const float*)d_in[3];
    const float* bq = (const float*)d_in[4];
    const float* Wv = (const float*)d_in[5];
    const float* bv = (const float*)d_in[6];
    float* out = (float*)d_out;
    char* ws = (char*)d_ws;
    f16* Wfrag = (f16*)(ws);                         // 393216 B
    f16* Qb    = (f16*)(ws + 393216);                // 2 MiB
    f16* Kb    = (f16*)(ws + 393216 + 2097152);      // 2 MiB
    f16* Vbt   = (f16*)(ws + 393216 + 2 * 2097152);  // 2 MiB (transposed)
    f16* Opart = (f16*)(ws + 393216 + 3 * 2097152);              // 16 MiB (2048 slots)
    float* Ml  = (float*)(ws + 393216 + 3 * 2097152 + 16777216); // 1 MiB

    prep_w<<<12, 256, 0, stream>>>(Wq, Wk, Wv, Wfrag);
    proj<<<1024, 256, 0, stream>>>(x, Wfrag, bk, bq, bv, Qb, Kb, Vbt);
    attn<<<dim3(288, 4), 256, 0, stream>>>(Qb, Kb, Vbt, Opart, Ml);
    combine<<<dim3(64, 4), 256, 0, stream>>>(Opart, Ml, out);
}